// Round 12
// baseline (407.211 us; speedup 1.0000x reference)
//
#include <hip/hip_runtime.h>
#include <cstdint>
#include <cstddef>

#define PI_F 3.14159265358979323846f

constexpr int BB = 4, NN = 512, BN = 2048, NBIN = 48;

typedef __attribute__((ext_vector_type(8))) short v8s;   // 8 bf16 (4 VGPRs)
typedef __attribute__((ext_vector_type(4))) float v4f;   // MFMA acc

__device__ __forceinline__ unsigned short f2bf(float f) {
  unsigned u = __float_as_uint(f);
  unsigned r = (u + 0x7FFFu + ((u >> 16) & 1u)) >> 16;   // RNE
  return (unsigned short)r;
}

// ---------------------------------------------------------------- steer into KT[n][iv] bf16
// n = k*(2O) + o*2 + u ; iv = i*2+v, rows padded to Kdpad with zeros for i>=I
__device__ __forceinline__ void steer_kt(const float* __restrict__ W,
                                         unsigned short* __restrict__ KT,
                                         int O, int I, int Ipad2, int Kdpad,
                                         int idx, int total) {
  if (idx >= total) return;
  int i = idx % Ipad2;
  int o = (idx / Ipad2) % O;
  int k = idx / (Ipad2 * O);
  size_t b0 = (size_t)(k*(2*O) + o*2 + 0) * Kdpad + i*2;
  size_t b1 = b0 + Kdpad;
  if (i >= I) { KT[b0]=0; KT[b0+1]=0; KT[b1]=0; KT[b1+1]=0; return; }
  int tt = k % 16;
  float ang = (tt + 0.5f) * (2.0f * PI_F / 16.0f) - PI_F;
  float ct = cosf(ang), st = sinf(ang);
  const float* Wp = W + ((size_t)(k*O + o)*I + i) * 4;
  float w00 = Wp[0], w01 = Wp[1], w10 = Wp[2], w11 = Wp[3];
  float rw00 = ct*w00 - st*w10, rw01 = ct*w01 - st*w11;
  float rw10 = st*w00 + ct*w10, rw11 = st*w01 + ct*w11;
  KT[b0 + 0] = f2bf(rw00*ct - rw01*st);   // u0 v0
  KT[b0 + 1] = f2bf(rw00*st + rw01*ct);   // u0 v1
  KT[b1 + 0] = f2bf(rw10*ct - rw11*st);   // u1 v0
  KT[b1 + 1] = f2bf(rw10*st + rw11*ct);   // u1 v1
}

// box steering: KO fp32, pair layout for fko_build
__device__ __forceinline__ void steer_ko(const float* __restrict__ W, float* __restrict__ KO,
                                         int idx) {
  if (idx >= 768) return;
  int o = idx % 16;
  int k = idx / 16;
  int tt = k % 16;
  float ang = (tt + 0.5f) * (2.0f * PI_F / 16.0f) - PI_F;
  float ct = cosf(ang), st = sinf(ang);
  const float* Wp = W + (size_t)(k*16 + o) * 4;
  float w00 = Wp[0], w01 = Wp[1], w10 = Wp[2], w11 = Wp[3];
  float rw00 = ct*w00 - st*w10, rw01 = ct*w01 - st*w11;
  float rw10 = st*w00 + ct*w10, rw11 = st*w01 + ct*w11;
  size_t n0 = (size_t)(k*32 + o*2) * 2;
  KO[n0 + 0] = rw00*ct - rw01*st;
  KO[n0 + 1] = rw00*st + rw01*ct;
  KO[n0 + 2] = rw10*ct - rw11*st;
  KO[n0 + 3] = rw10*st + rw11*ct;
}

// ---------------------------------------------------------------- setup: prep + all steers
__global__ __launch_bounds__(256) void setup_kernel(
    const float* __restrict__ p0, const float* __restrict__ v0,
    const float* __restrict__ a, const float* __restrict__ other,
    const float* __restrict__ v0enc, float* __restrict__ p1,
    float* __restrict__ F0, unsigned short* __restrict__ F0b,
    const float* Wcf, unsigned short* KT0f, const float* Wco, float* KO,
    const float* Wc1, unsigned short* KT1, const float* Wc2, unsigned short* KT2,
    const float* Wc3, unsigned short* KT3, const float* Wc4, unsigned short* KT4) {
  int blk = blockIdx.x;
  int t = threadIdx.x;
  if (blk < 8) {
    int n = blk * 256 + t;
    float p0x = p0[n*2], p0y = p0[n*2+1];
    float v0x = v0[n*2], v0y = v0[n*2+1];
    float ax = a[n*2],  ay = a[n*2+1];
    float v1x = v0x + 0.1f*ax, v1y = v0y + 0.1f*ay;
    p1[n*2]   = p0x + 0.1f*(v0x+v1x)*0.5f;
    p1[n*2+1] = p0y + 0.1f*(v0y+v1y)*0.5f;
    float F[64];
    F[0] = v1x; F[1] = v1y;
    for (int c = 0; c < 3; ++c) {
      F[2+c*2]   = other[(n*3+c)*2];
      F[2+c*2+1] = other[(n*3+c)*2+1];
    }
    for (int c = 0; c < 16; ++c) {
      F[8+c*2]   = v0enc[(n*16+c)*2];
      F[8+c*2+1] = v0enc[(n*16+c)*2+1];
    }
    for (int c = 40; c < 64; ++c) F[c] = 0.0f;
    float* Fo = F0 + (size_t)n*64;
    unsigned short* Fb = F0b + (size_t)n*64;
    for (int c = 0; c < 64; ++c) { Fo[c] = F[c]; Fb[c] = f2bf(F[c]); }
  } else if (blk < 104) steer_kt(Wcf, KT0f, 16, 20, 32, 64, (blk-8)*256 + t, 24576);
  else if (blk < 107) steer_ko(Wco, KO, (blk-104)*256 + t);
  else if (blk < 395) steer_kt(Wc1, KT1, 32, 48, 48, 96, (blk-107)*256 + t, 73728);
  else if (blk < 587) steer_kt(Wc2, KT2, 32, 32, 32, 64, (blk-395)*256 + t, 49152);
  else if (blk < 779) steer_kt(Wc3, KT3, 32, 32, 32, 64, (blk-587)*256 + t, 49152);
  else                steer_kt(Wc4, KT4, 1, 32, 32, 64, (blk-779)*256 + t, 1536);
}

// ---------------------------------------------------------------- pairs + compaction
__global__ __launch_bounds__(256) void pairs_all(const float* __restrict__ qry,
                                                 const float* __restrict__ srcF,
                                                 const float* __restrict__ maskF,
                                                 float* __restrict__ wlF, int* __restrict__ plF,
                                                 int* __restrict__ cntF,
                                                 const float* __restrict__ srcO,
                                                 const float* __restrict__ maskO,
                                                 float* __restrict__ wlO, int* __restrict__ plO,
                                                 int* __restrict__ cntO) {
  bool isBox = blockIdx.x >= 512;
  int qblk = isBox ? (blockIdx.x - 512) : blockIdx.x;
  const float* src = isBox ? srcO : srcF;
  const float* mask = isBox ? maskO : maskF;
  float* wlist = isBox ? wlO : wlF;
  int* plist = isBox ? plO : plF;
  int* cnt = isBox ? cntO : cntF;

  int wv = threadIdx.x >> 6;
  int lane = threadIdx.x & 63;
  int q = qblk * 4 + wv;
  int b = q >> 9;
  float qx = qry[q*2], qy = qry[q*2+1];
  const float* sb = src + b*1024;
  const float* mb = mask + (size_t)q*512;
  float* wl = wlist + (size_t)q*512;
  int* pl = plist + (size_t)q*512;
  int base = 0;
  for (int ch = 0; ch < 8; ++ch) {
    int s = ch*64 + lane;
    float sx = sb[s*2], sy = sb[s*2+1];
    float rx = sx - qx, ry = sy - qy;
    float d2 = rx*rx + ry*ry;
    float m = mb[s];
    float wi = fmaxf(1.0f - d2 / 1600.0f, 0.0f);
    float w = wi*wi*wi*m;
    bool pred = w > 0.0f;
    int k = 0;
    if (pred) {
      float dist = sqrtf(d2 + 1e-9f);
      float theta = atan2f(ry, rx);
      int rb = (int)(dist / 40.0f * 3.0f);
      rb = rb > 2 ? 2 : rb;
      float u = (theta + PI_F) / (2.0f * PI_F) * 16.0f;
      int tb = ((int)floorf(u)) & 15;
      k = rb*16 + tb;
    }
    unsigned long long msk = __ballot(pred);
    int before = __popcll(msk & ((1ull<<lane)-1ull));
    if (pred) {
      wl[base + before] = w;
      pl[base + before] = (s<<6) | k;
    }
    base += __popcll(msk);
  }
  if (lane == 0) cnt[q] = base;
}

// ---------------------------------------------------------------- FKo build (box, K=2, fp32 out)
__global__ __launch_bounds__(256) void fko_build(const float* __restrict__ boxf,
                                                 const float* __restrict__ KO,
                                                 float2* __restrict__ FKo2) {
  int idx = blockIdx.x * blockDim.x + threadIdx.x;   // s*768 + n2 (col pair)
  if (idx >= BN*768) return;
  int s = idx / 768, n2 = idx % 768;
  float b0 = boxf[s*2], b1 = boxf[s*2+1];
  float2 v;
  v.x = b0*KO[n2*4+0] + b1*KO[n2*4+1];
  v.y = b0*KO[n2*4+2] + b1*KO[n2*4+3];
  FKo2[idx] = v;
}

// ---------------------------------------------------------------- dense FK GEMM (bf16 MFMA, fp32 out)
// A [2048][Kd] bf16, B = KT [N][Kd] bf16, C = FK [2048][N] fp32
__global__ __launch_bounds__(256) void gemm_fk(const unsigned short* __restrict__ A,
                                               const unsigned short* __restrict__ B,
                                               float* __restrict__ C,
                                               int Kd, int N) {
  const int lane = threadIdx.x & 63;
  const int w = threadIdx.x >> 6;
  const int row0 = blockIdx.x * 32;
  const int colBase = (blockIdx.y * 4 + w) * 64;
  const int m = lane & 15, quad = lane >> 4;
  const unsigned short* Ar0 = A + (size_t)(row0 + m) * Kd + quad*8;
  const unsigned short* Ar1 = Ar0 + (size_t)16 * Kd;
  const unsigned short* Bp[4];
  #pragma unroll
  for (int nt = 0; nt < 4; ++nt)
    Bp[nt] = B + (size_t)(colBase + nt*16 + m) * Kd + quad*8;
  v4f acc[2][4];
  #pragma unroll
  for (int mt = 0; mt < 2; ++mt)
    for (int nt = 0; nt < 4; ++nt)
      acc[mt][nt] = (v4f){0.0f, 0.0f, 0.0f, 0.0f};
  for (int kt = 0; kt < Kd; kt += 32) {
    v8s a0 = *(const v8s*)(Ar0 + kt);
    v8s a1 = *(const v8s*)(Ar1 + kt);
    #pragma unroll
    for (int nt = 0; nt < 4; ++nt) {
      v8s bv = *(const v8s*)(Bp[nt] + kt);
      acc[0][nt] = __builtin_amdgcn_mfma_f32_16x16x32_bf16(a0, bv, acc[0][nt], 0, 0, 0);
      acc[1][nt] = __builtin_amdgcn_mfma_f32_16x16x32_bf16(a1, bv, acc[1][nt], 0, 0, 0);
    }
  }
  // D: col = lane&15, row = quad*4 + r
  #pragma unroll
  for (int mt = 0; mt < 2; ++mt)
    for (int nt = 0; nt < 4; ++nt)
      for (int r = 0; r < 4; ++r)
        C[(size_t)(row0 + mt*16 + quad*4 + r) * N + colBase + nt*16 + m] = acc[mt][nt][r];
}

// layer-4 FK GEMM: N=96, fp32 out
__global__ __launch_bounds__(256) void gemm_fk4(const unsigned short* __restrict__ A,
                                                const unsigned short* __restrict__ B,
                                                float* __restrict__ C, int Kd) {
  const int lane = threadIdx.x & 63;
  const int w = threadIdx.x >> 6;
  const int row0 = (blockIdx.x * 4 + w) * 32;
  const int m = lane & 15, quad = lane >> 4;
  const unsigned short* Ar0 = A + (size_t)(row0 + m) * Kd + quad*8;
  const unsigned short* Ar1 = Ar0 + (size_t)16 * Kd;
  const unsigned short* Bp[6];
  #pragma unroll
  for (int nt = 0; nt < 6; ++nt)
    Bp[nt] = B + (size_t)(nt*16 + m) * Kd + quad*8;
  v4f acc[2][6];
  #pragma unroll
  for (int mt = 0; mt < 2; ++mt)
    for (int nt = 0; nt < 6; ++nt)
      acc[mt][nt] = (v4f){0.0f, 0.0f, 0.0f, 0.0f};
  for (int kt = 0; kt < Kd; kt += 32) {
    v8s a0 = *(const v8s*)(Ar0 + kt);
    v8s a1 = *(const v8s*)(Ar1 + kt);
    #pragma unroll
    for (int nt = 0; nt < 6; ++nt) {
      v8s bv = *(const v8s*)(Bp[nt] + kt);
      acc[0][nt] = __builtin_amdgcn_mfma_f32_16x16x32_bf16(a0, bv, acc[0][nt], 0, 0, 0);
      acc[1][nt] = __builtin_amdgcn_mfma_f32_16x16x32_bf16(a1, bv, acc[1][nt], 0, 0, 0);
    }
  }
  #pragma unroll
  for (int mt = 0; mt < 2; ++mt)
    for (int nt = 0; nt < 6; ++nt)
      for (int r = 0; r < 4; ++r)
        C[(size_t)(row0 + mt*16 + quad*4 + r) * 96 + nt*16 + m] = acc[mt][nt][r];
}

// ---------------------------------------------------------------- gather core (fp32 FK) — stage-0 (32 comps)
__device__ __forceinline__ float gather_loop(const float* __restrict__ FK, int N,
                                             const float* __restrict__ wl,
                                             const int* __restrict__ pl,
                                             int nnz, int rowbase, int ou, int j, int OUc) {
  float acc = 0.0f;
  float wA[4], fA[4];
  #pragma unroll
  for (int jj = 0; jj < 4; ++jj) {
    int idx = j + jj*2;
    bool v = idx < nnz;
    float w = v ? wl[idx] : 0.0f;
    int p = v ? pl[idx] : 0;
    wA[jj] = w;
    fA[jj] = FK[(size_t)(rowbase + (p >> 6)) * N + (p & 63)*OUc + ou];
  }
  for (int base = 0; base < nnz; base += 8) {
    float wB[4], fB[4];
    #pragma unroll
    for (int jj = 0; jj < 4; ++jj) {
      int idx = base + 8 + j + jj*2;
      bool v = idx < nnz;
      float w = v ? wl[idx] : 0.0f;
      int p = v ? pl[idx] : 0;
      wB[jj] = w;
      fB[jj] = FK[(size_t)(rowbase + (p >> 6)) * N + (p & 63)*OUc + ou];
    }
    #pragma unroll
    for (int jj = 0; jj < 4; ++jj) acc = fmaf(wA[jj], fA[jj], acc);
    #pragma unroll
    for (int jj = 0; jj < 4; ++jj) { wA[jj] = wB[jj]; fA[jj] = fB[jj]; }
  }
  return acc;
}

__device__ __forceinline__ float nonlin(float x) {
  float p = __shfl_xor(x, 1);
  float m = x*x + p*p + 1e-6f;
  return x * fmaxf(m - 0.2f, 0.0f) / m;
}

// ---------------------------------------------------------------- stage-0 gather (+ dense + nonlin)
// O=16 per conv -> 32 components; ou = lane&31, entries split over j = lane>>5
__global__ __launch_bounds__(256) void gather0(const float* __restrict__ FKf,
                                               const float* __restrict__ FKo,
                                               const float* __restrict__ wlF, const int* __restrict__ plF,
                                               const int* __restrict__ cntF,
                                               const float* __restrict__ wlO, const int* __restrict__ plO,
                                               const int* __restrict__ cntO,
                                               const float* __restrict__ F0,
                                               const float* __restrict__ Adf, const float* __restrict__ Bdf,
                                               float* __restrict__ IN1, unsigned short* __restrict__ IN1b) {
  const int lane = threadIdx.x & 63;
  const int q = blockIdx.x * 4 + (threadIdx.x >> 6);
  const int j = lane >> 5, ou = lane & 31;
  const int rowbase = (q >> 9) * 512;
  float accF = gather_loop(FKf, 1536, wlF + (size_t)q*512, plF + (size_t)q*512, cntF[q], rowbase, ou, j, 32);
  accF += __shfl_down(accF, 32);
  float accO = gather_loop(FKo, 1536, wlO + (size_t)q*512, plO + (size_t)q*512, cntO[q], rowbase, ou, j, 32);
  accO += __shfl_down(accO, 32);
  const int o = ou >> 1, u = ou & 1;
  const float* f = F0 + (size_t)q * 64;
  float accD = 0.0f;
  for (int i = 0; i < 20; ++i) {
    float av = Adf[o*20+i], bv = Bdf[o*20+i];
    float fx = f[i*2], fy = f[i*2+1];
    accD += u ? (av*fy + bv*fx) : (av*fx - bv*fy);
  }
  float vO = nonlin(accO), vF = nonlin(accF), vD = nonlin(accD);
  if (lane < 32) {
    size_t bo = (size_t)q * 96;
    IN1[bo + ou] = vO;        IN1b[bo + ou] = f2bf(vO);
    IN1[bo + 32 + ou] = vF;   IN1b[bo + 32 + ou] = f2bf(vF);
    IN1[bo + 64 + ou] = vD;   IN1b[bo + 64 + ou] = f2bf(vD);
  }
}

// ---------------------------------------------------------------- layer gather (+ dense + residual + nonlin)
// O=32 -> 64 components; ALL 64 lanes are channels (lane = o*2+u); each lane walks all entries
template<int I, bool RES>
__global__ __launch_bounds__(256) void gatherL(const float* __restrict__ FK,
                                               const float* __restrict__ wl, const int* __restrict__ pl,
                                               const int* __restrict__ cnt,
                                               const float* __restrict__ INp,
                                               const float* __restrict__ Ad, const float* __restrict__ Bd,
                                               const float* __restrict__ prevOut,
                                               float* __restrict__ outCur,
                                               float* __restrict__ INn, unsigned short* __restrict__ INnb) {
  const int lane = threadIdx.x & 63;
  const int q = blockIdx.x * 4 + (threadIdx.x >> 6);
  const int rowbase = (q >> 9) * 512;
  const int nnz = cnt[q];
  const float* wlq = wl + (size_t)q*512;
  const int* plq = pl + (size_t)q*512;
  float acc = 0.0f;
  float wA[4], fA[4];
  #pragma unroll
  for (int jj = 0; jj < 4; ++jj) {
    bool v = jj < nnz;
    float w = v ? wlq[jj] : 0.0f;
    int p = v ? plq[jj] : 0;
    wA[jj] = w;
    fA[jj] = FK[(size_t)(rowbase + (p >> 6)) * 3072 + (p & 63)*64 + lane];
  }
  for (int base = 0; base < nnz; base += 4) {
    float wB[4], fB[4];
    #pragma unroll
    for (int jj = 0; jj < 4; ++jj) {
      int idx = base + 4 + jj;
      bool v = idx < nnz;
      float w = v ? wlq[idx] : 0.0f;
      int p = v ? plq[idx] : 0;
      wB[jj] = w;
      fB[jj] = FK[(size_t)(rowbase + (p >> 6)) * 3072 + (p & 63)*64 + lane];
    }
    #pragma unroll
    for (int jj = 0; jj < 4; ++jj) acc = fmaf(wA[jj], fA[jj], acc);
    #pragma unroll
    for (int jj = 0; jj < 4; ++jj) { wA[jj] = wB[jj]; fA[jj] = fB[jj]; }
  }
  const int o = lane >> 1, u = lane & 1;
  const float* f = INp + (size_t)q * I * 2;
  for (int i = 0; i < I; ++i) {
    float av = Ad[o*I+i], bv = Bd[o*I+i];
    float fx = f[i*2], fy = f[i*2+1];
    acc += u ? (av*fy + bv*fx) : (av*fx - bv*fy);
  }
  if (RES) acc += prevOut[(size_t)q*64 + lane];
  float v = nonlin(acc);
  outCur[(size_t)q*64 + lane] = acc;
  INn[(size_t)q*64 + lane] = v;
  INnb[(size_t)q*64 + lane] = f2bf(v);
}

// ---------------------------------------------------------------- final: layer4 gather + dense + correction
__global__ __launch_bounds__(256) void final_gather(const float* __restrict__ FK4,
                                                    const float* __restrict__ wl, const int* __restrict__ pl,
                                                    const int* __restrict__ cnt,
                                                    const float* __restrict__ IN4,
                                                    const float* __restrict__ Ad4, const float* __restrict__ Bd4,
                                                    const float* __restrict__ p1, const float* __restrict__ p0,
                                                    float* __restrict__ dout) {
  const int lane = threadIdx.x & 63;
  const int q = blockIdx.x * 4 + (threadIdx.x >> 6);
  const int u = lane & 1, ep = lane >> 1;
  const int rowbase = (q >> 9) * 512;
  const int nnz = cnt[q];
  const float* wlq = wl + (size_t)q*512;
  const int* plq = pl + (size_t)q*512;
  float acc = 0.0f;
  for (int base = 0; base < nnz; base += 32) {
    int idx = base + ep;
    bool v = idx < nnz;
    float w = v ? wlq[idx] : 0.0f;
    int p = v ? plq[idx] : 0;
    acc += w * FK4[(size_t)(rowbase + (p >> 6)) * 96 + (p & 63)*2 + u];
  }
  #pragma unroll
  for (int msk = 2; msk <= 32; msk <<= 1) acc += __shfl_xor(acc, msk);
  const float* f = IN4 + (size_t)q * 64;
  float d = 0.0f;
  for (int i = 0; i < 32; ++i) {
    float av = Ad4[i], bv = Bd4[i];
    float fx = f[i*2], fy = f[i*2+1];
    d += u ? (av*fy + bv*fx) : (av*fx - bv*fy);
  }
  if (lane < 2) {
    float corr = (acc + d) / 128.0f;
    float pc = p1[q*2 + u] + corr;
    dout[q*2 + u] = pc;
    dout[4096 + q*2 + u] = (pc - p0[q*2 + u]) / 0.1f;
  }
}

// ---------------------------------------------------------------- launch
extern "C" void kernel_launch(void* const* d_in, const int* in_sizes, int n_in,
                              void* d_out, int out_size, void* d_ws, size_t ws_size,
                              hipStream_t stream) {
  (void)in_sizes; (void)n_in; (void)out_size; (void)ws_size;
  const float* v0_enc = (const float*)d_in[1];
  const float* p0     = (const float*)d_in[2];
  const float* v0     = (const float*)d_in[3];
  const float* a      = (const float*)d_in[4];
  const float* other  = (const float*)d_in[5];
  const float* box    = (const float*)d_in[6];
  const float* boxf   = (const float*)d_in[7];
  const float* fmask  = (const float*)d_in[8];
  const float* bmask  = (const float*)d_in[9];
  const float* Wcf = (const float*)d_in[10];
  const float* Wco = (const float*)d_in[11];
  const float* Adf = (const float*)d_in[12];
  const float* Bdf = (const float*)d_in[13];
  const float* Wc1 = (const float*)d_in[14];
  const float* Ad1 = (const float*)d_in[15];
  const float* Bd1 = (const float*)d_in[16];
  const float* Wc2 = (const float*)d_in[17];
  const float* Ad2 = (const float*)d_in[18];
  const float* Bd2 = (const float*)d_in[19];
  const float* Wc3 = (const float*)d_in[20];
  const float* Ad3 = (const float*)d_in[21];
  const float* Bd3 = (const float*)d_in[22];
  const float* Wc4 = (const float*)d_in[23];
  const float* Ad4 = (const float*)d_in[24];
  const float* Bd4 = (const float*)d_in[25];

  float* ws = (float*)d_ws;
  // ---- workspace layout (floats); F0b correctly sized this time (65536 f) ----
  float*          P1   = ws + 0;                               //       0 .. 4096
  float*          F0   = ws + 4096;                            //    4096 .. 135168  (2048x64 f32)
  unsigned short* F0b  = (unsigned short*)(ws + 135168);       //  135168 .. 200704  (2048x64 bf16 = 65536 f)
  unsigned short* KT0f = (unsigned short*)(ws + 200704);       //  200704 .. 249856  (1536x64 bf16 = 49152 f)
  float*          KO   = ws + 249856;                          //  249856 .. 252928  (3072 f)
  unsigned short* KT1  = (unsigned short*)(ws + 252928);       //  252928 .. 400384  (3072x96 bf16 = 147456 f)
  unsigned short* KT2  = (unsigned short*)(ws + 400384);       //  400384 .. 498688  (3072x64 bf16 = 98304 f)
  unsigned short* KT3  = (unsigned short*)(ws + 498688);       //  498688 .. 596992
  unsigned short* KT4  = (unsigned short*)(ws + 596992);       //  596992 .. 600064  (96x64 bf16 = 3072 f)
  float*          WFl  = ws + 600064;                          //  600064 .. 1648640
  int*            PFl  = (int*)(ws + 1648640);                 // 1648640 .. 2697216
  float*          WOl  = ws + 2697216;                         // 2697216 .. 3745792
  int*            POl  = (int*)(ws + 3745792);                 // 3745792 .. 4794368
  int*            CNTF = (int*)(ws + 4794368);                 // 4794368 .. 4796416
  int*            CNTO = (int*)(ws + 4796416);                 // 4796416 .. 4798464
  float*          IN1  = ws + 4798464;                         // 4798464 .. 4995072  (2048x96)
  unsigned short* IN1b = (unsigned short*)(ws + 4995072);      // 4995072 .. 5093376  (98304 f)
  float*          IN2  = ws + 5093376;                         // 5093376 .. 5224448  (2048x64)
  unsigned short* IN2b = (unsigned short*)(ws + 5224448);      // 5224448 .. 5289984  (65536 f)
  float*          IN3  = ws + 5289984;                         // 5289984 .. 5421056
  unsigned short* IN3b = (unsigned short*)(ws + 5421056);      // 5421056 .. 5486592
  float*          IN4  = ws + 5486592;                         // 5486592 .. 5617664
  unsigned short* IN4b = (unsigned short*)(ws + 5617664);      // 5617664 .. 5683200
  float*          OUTA = ws + 5683200;                         // 5683200 .. 5814272
  float*          OUTB = ws + 5814272;                         // 5814272 .. 5945344
  float*          FK4  = ws + 5945344;                         // 5945344 .. 6141952  (2048x96)
  float*          FKf0 = ws + 6141952;                         // 6141952 .. 9287680  (2048x1536)
  float*          FKo  = ws + 9287680;                         // 9287680 .. 12433408 (2048x1536)
  // FK (2048x3072 f32 = 6291456) aliases FKf0+FKo exactly; both dead after gather0
  float*          FK   = ws + 6141952;                         // end 12433408 f = 49.7 MB

  setup_kernel<<<785, 256, 0, stream>>>(p0, v0, a, other, v0_enc, P1, F0, F0b,
                                        Wcf, KT0f, Wco, KO, Wc1, KT1,
                                        Wc2, KT2, Wc3, KT3, Wc4, KT4);
  pairs_all<<<1024, 256, 0, stream>>>(P1, P1, fmask, WFl, PFl, CNTF,
                                      box, bmask, WOl, POl, CNTO);

  // stage 0: FK tables + fused gather/dense/nonlin
  fko_build<<<6144, 256, 0, stream>>>(boxf, KO, (float2*)FKo);
  gemm_fk<<<dim3(64, 6), 256, 0, stream>>>(F0b, KT0f, FKf0, 64, 1536);
  gather0<<<512, 256, 0, stream>>>(FKf0, FKo, WFl, PFl, CNTF, WOl, POl, CNTO,
                                   F0, Adf, Bdf, IN1, IN1b);

  // layer 1: I=48 -> O=32
  gemm_fk<<<dim3(64, 12), 256, 0, stream>>>(IN1b, KT1, FK, 96, 3072);
  gatherL<48, false><<<512, 256, 0, stream>>>(FK, WFl, PFl, CNTF, IN1, Ad1, Bd1,
                                              nullptr, OUTA, IN2, IN2b);

  // layer 2: I=32 -> O=32, residual
  gemm_fk<<<dim3(64, 12), 256, 0, stream>>>(IN2b, KT2, FK, 64, 3072);
  gatherL<32, true><<<512, 256, 0, stream>>>(FK, WFl, PFl, CNTF, IN2, Ad2, Bd2,
                                             OUTA, OUTB, IN3, IN3b);

  // layer 3: I=32 -> O=32, residual
  gemm_fk<<<dim3(64, 12), 256, 0, stream>>>(IN3b, KT3, FK, 64, 3072);
  gatherL<32, true><<<512, 256, 0, stream>>>(FK, WFl, PFl, CNTF, IN3, Ad3, Bd3,
                                             OUTB, OUTA, IN4, IN4b);

  // layer 4: I=32 -> O=1, fused gather + dense + apply_correction
  gemm_fk4<<<16, 256, 0, stream>>>(IN4b, KT4, FK4, 64);
  final_gather<<<512, 256, 0, stream>>>(FK4, WFl, PFl, CNTF, IN4, Ad4, Bd4,
                                        P1, p0, (float*)d_out);
}